// Round 1
// baseline (4066.480 us; speedup 1.0000x reference)
//
#include <hip/hip_runtime.h>
#include <math.h>

// ============================================================================
// VL_SAE: recon/latent for vision+text sparse autoencoder
// N=4096, D=768, H=16384, topk=32
// Round 1: correctness-first all-fp32 pipeline:
//   1) row_invnorm  (encoder, emb_v, emb_t)
//   2) gemm_sim     fp32 128x128x16 SGEMM, epilogue: scale + 2-sqrt(2-2cos)
//                   writes sim directly into d_out latent region
//   3) select       per-row radix-select 33rd-largest(|sim|), mask in place,
//                   emit compact (idx,val) lists to ws
//   4) transpose    Wv,Wt -> WT in ws (coalesced gather for recon)
//   5) recon        out[n,d] = b[d] + sum_j val_j * WT[h_j][d]
// ============================================================================

#define N_ROWS 4096
#define D_DIM  768
#define H_DIM  16384

#define BM 128
#define BN 128
#define BK 16

// ---------------------------------------------------------------------------
__global__ void row_invnorm_kernel(const float* __restrict__ x,
                                   float* __restrict__ inv, int rows) {
    int row = blockIdx.x * 4 + (threadIdx.x >> 6);
    int lane = threadIdx.x & 63;
    if (row >= rows) return;
    const float4* p = reinterpret_cast<const float4*>(x + (size_t)row * D_DIM);
    float ss = 0.f;
    #pragma unroll
    for (int i = 0; i < 3; i++) {           // 192 float4 per row / 64 lanes
        float4 v = p[lane + i * 64];
        ss += v.x * v.x + v.y * v.y + v.z * v.z + v.w * v.w;
    }
    #pragma unroll
    for (int off = 32; off > 0; off >>= 1) ss += __shfl_down(ss, off);
    if (lane == 0) inv[row] = 1.f / fmaxf(sqrtf(ss), 1e-12f);
}

// ---------------------------------------------------------------------------
// C[n,h] = 2 - sqrt(max(2 - 2*dot(A_n,enc_h)*invA[n]*invB[h], 0))
__global__ __launch_bounds__(256)
void gemm_sim_kernel(const float* __restrict__ embv,
                     const float* __restrict__ embt,
                     const float* __restrict__ enc,
                     const float* __restrict__ inv_emb,   // [2][N_ROWS]
                     const float* __restrict__ inv_enc,   // [H_DIM]
                     float* __restrict__ latent)          // [2][N_ROWS][H_DIM]
{
    int z = blockIdx.z;
    const float* A = z ? embt : embv;
    const float* invA = inv_emb + z * N_ROWS;
    float* C = latent + (size_t)z * N_ROWS * H_DIM;

    __shared__ float As[BK][BM + 4];
    __shared__ float Bs[BK][BN + 4];

    int tid = threadIdx.x;
    int tx = tid & 15;        // col group 0..15 (8 cols each)
    int ty = tid >> 4;        // row group 0..15 (8 rows each)
    int row0 = blockIdx.y * BM;
    int col0 = blockIdx.x * BN;

    float acc[8][8];
    #pragma unroll
    for (int i = 0; i < 8; i++)
        #pragma unroll
        for (int j = 0; j < 8; j++) acc[i][j] = 0.f;

    for (int k0 = 0; k0 < D_DIM; k0 += BK) {
        #pragma unroll
        for (int t = 0; t < 2; t++) {
            int idx = t * 256 + tid;        // 0..511
            int r = idx >> 2;               // 0..127
            int c4 = idx & 3;               // which float4 of the 16-wide k slab
            float4 va = *reinterpret_cast<const float4*>(
                A + (size_t)(row0 + r) * D_DIM + k0 + c4 * 4);
            As[c4 * 4 + 0][r] = va.x; As[c4 * 4 + 1][r] = va.y;
            As[c4 * 4 + 2][r] = va.z; As[c4 * 4 + 3][r] = va.w;
            float4 vb = *reinterpret_cast<const float4*>(
                enc + (size_t)(col0 + r) * D_DIM + k0 + c4 * 4);
            Bs[c4 * 4 + 0][r] = vb.x; Bs[c4 * 4 + 1][r] = vb.y;
            Bs[c4 * 4 + 2][r] = vb.z; Bs[c4 * 4 + 3][r] = vb.w;
        }
        __syncthreads();
        #pragma unroll
        for (int kk = 0; kk < BK; kk++) {
            float a[8], b[8];
            *reinterpret_cast<float4*>(&a[0]) =
                *reinterpret_cast<const float4*>(&As[kk][ty * 8]);
            *reinterpret_cast<float4*>(&a[4]) =
                *reinterpret_cast<const float4*>(&As[kk][ty * 8 + 4]);
            *reinterpret_cast<float4*>(&b[0]) =
                *reinterpret_cast<const float4*>(&Bs[kk][tx * 8]);
            *reinterpret_cast<float4*>(&b[4]) =
                *reinterpret_cast<const float4*>(&Bs[kk][tx * 8 + 4]);
            #pragma unroll
            for (int i = 0; i < 8; i++)
                #pragma unroll
                for (int j = 0; j < 8; j++)
                    acc[i][j] = fmaf(a[i], b[j], acc[i][j]);
        }
        __syncthreads();
    }

    #pragma unroll
    for (int i = 0; i < 8; i++) {
        int n = row0 + ty * 8 + i;
        float sa = invA[n];
        float* Crow = C + (size_t)n * H_DIM + col0 + tx * 8;
        float4 o0, o1;
        float tmp[8];
        #pragma unroll
        for (int j = 0; j < 8; j++) {
            float cosv = acc[i][j] * sa * inv_enc[col0 + tx * 8 + j];
            float sim = 2.f - sqrtf(fmaxf(2.f - 2.f * cosv, 0.f));
            tmp[j] = sim;
        }
        o0.x = tmp[0]; o0.y = tmp[1]; o0.z = tmp[2]; o0.w = tmp[3];
        o1.x = tmp[4]; o1.y = tmp[5]; o1.z = tmp[6]; o1.w = tmp[7];
        *reinterpret_cast<float4*>(Crow) = o0;
        *reinterpret_cast<float4*>(Crow + 4) = o1;
    }
}

// ---------------------------------------------------------------------------
// Per row: radix-select the (topk+1)-th largest |sim|, zero entries with
// |sim| <= thres in place, emit compact (idx, val) list for recon.
__global__ void select_kernel(float* __restrict__ latent,
                              const int* __restrict__ topk_p,
                              int* __restrict__ sel_cnt,
                              int* __restrict__ sel_idx,
                              float* __restrict__ sel_val)
{
    int row = blockIdx.x;                 // 0..2*N_ROWS-1
    float* v = latent + (size_t)row * H_DIM;
    int tid = threadIdx.x;

    __shared__ unsigned hist[256];
    __shared__ unsigned s_prefix;
    __shared__ int s_k;
    __shared__ int s_cnt;

    int k = topk_p[0] + 1;                // 33rd largest
    unsigned prefix = 0;

    for (int shift = 24; shift >= 0; shift -= 8) {
        hist[tid] = 0;
        __syncthreads();
        unsigned pmask = (shift == 24) ? 0u : (0xFFFFFFFFu << (shift + 8));
        for (int i = tid; i < H_DIM; i += 256) {
            unsigned u = __float_as_uint(v[i]) & 0x7FFFFFFFu;  // |sim| key
            if ((u & pmask) == prefix)
                atomicAdd(&hist[(u >> shift) & 255u], 1u);
        }
        __syncthreads();
        if (tid == 0) {
            int c = 0, b = 255;
            for (; b >= 0; b--) {
                c += (int)hist[b];
                if (c >= k) break;
            }
            if (b < 0) b = 0;             // unreachable by invariant
            s_prefix = prefix | ((unsigned)b << shift);
            s_k = k - (c - (int)hist[b]);
        }
        __syncthreads();
        prefix = s_prefix;
        k = s_k;
        __syncthreads();
    }

    float thres = __uint_as_float(prefix);
    if (tid == 0) s_cnt = 0;
    __syncthreads();

    for (int i = tid; i < H_DIM; i += 256) {
        float x = v[i];
        bool keep = (fabsf(x) > thres);   // strict >, matches reference mask
        v[i] = keep ? x : 0.f;
        if (keep) {
            int slot = atomicAdd(&s_cnt, 1);
            if (slot < 40) {
                sel_idx[(size_t)row * 40 + slot] = i;
                sel_val[(size_t)row * 40 + slot] = x;
            }
        }
    }
    __syncthreads();
    if (tid == 0) sel_cnt[row] = (s_cnt > 40) ? 40 : s_cnt;
}

// ---------------------------------------------------------------------------
__global__ void transpose_kernel(const float* __restrict__ Wv,
                                 const float* __restrict__ Wt,
                                 float* __restrict__ WvT,
                                 float* __restrict__ WtT)
{
    int z = blockIdx.z;
    const float* W = z ? Wt : Wv;         // [D_DIM][H_DIM]
    float* WT = z ? WtT : WvT;            // [H_DIM][D_DIM]
    __shared__ float tile[32][33];
    int tx = threadIdx.x & 31;
    int ty = threadIdx.x >> 5;            // 0..7
    int h0 = blockIdx.x * 32;
    int d0 = blockIdx.y * 32;
    #pragma unroll
    for (int t = 0; t < 4; t++)
        tile[ty + t * 8][tx] = W[(size_t)(d0 + ty + t * 8) * H_DIM + h0 + tx];
    __syncthreads();
    #pragma unroll
    for (int t = 0; t < 4; t++)
        WT[(size_t)(h0 + ty + t * 8) * D_DIM + d0 + tx] = tile[tx][ty + t * 8];
}

// ---------------------------------------------------------------------------
// out[n,d] = bias[d] + sum_j val_j * W[idx_j*sh + d*sd]
// transpose path: sh=D_DIM, sd=1 (coalesced). fallback: sh=1, sd=H_DIM.
__global__ void recon_kernel(const float* __restrict__ Wv_,
                             const float* __restrict__ Wt_,
                             const float* __restrict__ bv,
                             const float* __restrict__ bt,
                             const int* __restrict__ sel_cnt,
                             const int* __restrict__ sel_idx,
                             const float* __restrict__ sel_val,
                             long sh, long sd,
                             float* __restrict__ out)     // [2][N_ROWS][D_DIM]
{
    int n = blockIdx.x;
    int z = blockIdx.y;
    int row = z * N_ROWS + n;
    const float* W = z ? Wt_ : Wv_;
    const float* bias = z ? bt : bv;
    float* o = out + (size_t)z * N_ROWS * D_DIM + (size_t)n * D_DIM;

    __shared__ int s_idx[40];
    __shared__ float s_val[40];
    __shared__ int s_cnt;
    int tid = threadIdx.x;
    if (tid == 0) s_cnt = sel_cnt[row];
    __syncthreads();
    int cnt = s_cnt;
    if (tid < cnt) {
        s_idx[tid] = sel_idx[(size_t)row * 40 + tid];
        s_val[tid] = sel_val[(size_t)row * 40 + tid];
    }
    __syncthreads();

    for (int d = tid; d < D_DIM; d += 256) {
        float acc = bias[d];
        for (int j = 0; j < cnt; j++)
            acc += s_val[j] * W[(size_t)s_idx[j] * sh + (size_t)d * sd];
        o[d] = acc;
    }
}

// ---------------------------------------------------------------------------
extern "C" void kernel_launch(void* const* d_in, const int* in_sizes, int n_in,
                              void* d_out, int out_size, void* d_ws, size_t ws_size,
                              hipStream_t stream) {
    const float* embv = (const float*)d_in[0];
    const float* embt = (const float*)d_in[1];
    const float* enc  = (const float*)d_in[2];
    const float* Wv   = (const float*)d_in[3];
    const float* bv   = (const float*)d_in[4];
    const float* Wt   = (const float*)d_in[5];
    const float* bt   = (const float*)d_in[6];
    const int* topk   = (const int*)d_in[7];
    float* out = (float*)d_out;

    char* ws = (char*)d_ws;
    size_t off = 0;
    float* inv_enc = (float*)(ws + off); off += (size_t)H_DIM * 4;
    float* inv_emb = (float*)(ws + off); off += (size_t)2 * N_ROWS * 4;
    int*   sel_cnt = (int*)(ws + off);   off += (size_t)2 * N_ROWS * 4;
    int*   sel_idx = (int*)(ws + off);   off += (size_t)2 * N_ROWS * 40 * 4;
    float* sel_val = (float*)(ws + off); off += (size_t)2 * N_ROWS * 40 * 4;
    float* WvT = (float*)(ws + off);
    float* WtT = WvT + (size_t)D_DIM * H_DIM;
    bool use_T = ws_size >= off + (size_t)2 * D_DIM * H_DIM * 4;

    float* recon_out = out;                                  // [2][N][D]
    float* latent = out + (size_t)2 * N_ROWS * D_DIM;        // [2][N][H]

    row_invnorm_kernel<<<H_DIM / 4, 256, 0, stream>>>(enc, inv_enc, H_DIM);
    row_invnorm_kernel<<<N_ROWS / 4, 256, 0, stream>>>(embv, inv_emb, N_ROWS);
    row_invnorm_kernel<<<N_ROWS / 4, 256, 0, stream>>>(embt, inv_emb + N_ROWS, N_ROWS);

    dim3 g(H_DIM / BN, N_ROWS / BM, 2);
    gemm_sim_kernel<<<g, 256, 0, stream>>>(embv, embt, enc, inv_emb, inv_enc, latent);

    select_kernel<<<2 * N_ROWS, 256, 0, stream>>>(latent, topk, sel_cnt, sel_idx, sel_val);

    if (use_T) {
        transpose_kernel<<<dim3(H_DIM / 32, D_DIM / 32, 2), 256, 0, stream>>>(
            Wv, Wt, WvT, WtT);
        recon_kernel<<<dim3(N_ROWS, 2), 256, 0, stream>>>(
            WvT, WtT, bv, bt, sel_cnt, sel_idx, sel_val, (long)D_DIM, 1L, recon_out);
    } else {
        recon_kernel<<<dim3(N_ROWS, 2), 256, 0, stream>>>(
            Wv, Wt, bv, bt, sel_cnt, sel_idx, sel_val, 1L, (long)H_DIM, recon_out);
    }
}

// Round 2
// 1863.666 us; speedup vs baseline: 2.1820x; 2.1820x over previous
//
#include <hip/hip_runtime.h>
#include <math.h>

// ============================================================================
// VL_SAE: N=4096, D=768, H=16384, topk=32
// Round 2: bf16x2-split MFMA GEMM (3 products) + histogram select +
//          eps-margin exact-fp32 boundary refinement.
//   split     normalize rows, split into bf16 hi/lo (RNE both)
//   gemm_mfma 128x128 tile, 16x16x32 bf16 MFMA, global_load_lds(16B),
//             epilogue sim = 2 - sqrt(max(2-2cos,0)) -> latent (d_out)
//   hist      per-row 1024-bin histogram of |sim| -> bin of 33rd largest
//   select2   collect candidates (key >= bin), exact rank among approx,
//             v* = 33rd approx; classify certain-keep / certain-drop /
//             ambiguous (|v - v*| <= MARGIN); zero the drops
//   refine    exact fp32 dots for ambiguous, np-exact tie-aware top-off
//   transpose + recon (gather of <=32 rows of W^T)
// Legacy all-fp32 path retained as fallback for small ws_size.
// ============================================================================

#define N_ROWS 4096
#define D_DIM  768
#define H_DIM  16384
#define M_TOT  8192
#define TOPK   32
#define KSEL   33
#define MARGIN 5e-4f
#define SEL_CAP 40
#define AMB_CAP 64
#define CAND_CAP 1024
#define BINS 1024
#define BIN_OFF (121 << 7)   // bins cover [2^-6, 4)

typedef __attribute__((ext_vector_type(8))) short short8;
typedef __attribute__((ext_vector_type(4))) float floatx4;

__device__ inline unsigned short bf16_rne(float f) {
    unsigned u = __float_as_uint(f);
    unsigned r = u + 0x7fffu + ((u >> 16) & 1u);
    return (unsigned short)(r >> 16);
}

__device__ inline void gload16(const unsigned short* g, unsigned short* l) {
    __builtin_amdgcn_global_load_lds(
        (const __attribute__((address_space(1))) void*)g,
        (__attribute__((address_space(3))) void*)l, 16, 0, 0);
}

// ---------------------------------------------------------------------------
// normalize one row (768 f32) and write bf16 hi/lo splits + inv-norm
__global__ void split_kernel(const float* __restrict__ src,
                             unsigned short* __restrict__ hi,
                             unsigned short* __restrict__ lo,
                             float* __restrict__ inv_out)
{
    int row = blockIdx.x;
    int tid = threadIdx.x;
    __shared__ float red[4];
    const float4* s4 = reinterpret_cast<const float4*>(src + (size_t)row * D_DIM);
    float4 v = make_float4(0.f, 0.f, 0.f, 0.f);
    float ss = 0.f;
    if (tid < 192) {
        v = s4[tid];
        ss = v.x * v.x + v.y * v.y + v.z * v.z + v.w * v.w;
    }
    #pragma unroll
    for (int o = 32; o > 0; o >>= 1) ss += __shfl_down(ss, o);
    int wave = tid >> 6, lane = tid & 63;
    if (lane == 0) red[wave] = ss;
    __syncthreads();
    if (tid == 0) {
        float tot = red[0] + red[1] + red[2];
        red[0] = 1.f / fmaxf(sqrtf(tot), 1e-12f);
    }
    __syncthreads();
    float inv = red[0];
    if (tid == 0) inv_out[row] = inv;
    if (tid < 192) {
        float x[4] = {v.x * inv, v.y * inv, v.z * inv, v.w * inv};
        ushort4 h4, l4;
        unsigned short hh[4], ll[4];
        #pragma unroll
        for (int t = 0; t < 4; t++) {
            hh[t] = bf16_rne(x[t]);
            float hf = __uint_as_float((unsigned)hh[t] << 16);
            ll[t] = bf16_rne(x[t] - hf);
        }
        h4.x = hh[0]; h4.y = hh[1]; h4.z = hh[2]; h4.w = hh[3];
        l4.x = ll[0]; l4.y = ll[1]; l4.z = ll[2]; l4.w = ll[3];
        size_t base = (size_t)row * D_DIM + tid * 4;
        *reinterpret_cast<ushort4*>(hi + base) = h4;
        *reinterpret_cast<ushort4*>(lo + base) = l4;
    }
}

// ---------------------------------------------------------------------------
// C[n,h]: bf16x2 split MFMA GEMM, inputs pre-normalized so cos = acc.
// LDS chunk permutation p(r,q) = (r>>3)*32 + q*8 + (r&7)  (16B chunks)
// -> ds_read_b128 fragment loads are 2-way-conflict only (free).
#define GBK 32

__global__ __launch_bounds__(256, 3)
void gemm_mfma_kernel(const unsigned short* __restrict__ Ahi,
                      const unsigned short* __restrict__ Alo,
                      const unsigned short* __restrict__ Bhi,
                      const unsigned short* __restrict__ Blo,
                      float* __restrict__ latent)
{
    __shared__ unsigned short sA[2][128 * GBK];
    __shared__ unsigned short sB[2][128 * GBK];

    int tid = threadIdx.x;
    int lane = tid & 63;
    int wave = tid >> 6;
    int wr = (wave >> 1) * 64;
    int wc = (wave & 1) * 64;
    int m = lane & 15;
    int q = lane >> 4;

    int row0 = blockIdx.y * 128;
    int col0 = blockIdx.x * 128;

    // staging: thread loads chunks p0 = tid, p1 = tid+256 of each matrix
    int p0 = tid, p1 = tid + 256;
    int r0 = ((p0 >> 5) << 3) | (p0 & 7), q0 = (p0 >> 3) & 3;
    int r1 = ((p1 >> 5) << 3) | (p1 & 7), q1 = (p1 >> 3) & 3;
    size_t aoff0 = (size_t)(row0 + r0) * D_DIM + q0 * 8;
    size_t aoff1 = (size_t)(row0 + r1) * D_DIM + q1 * 8;
    size_t boff0 = (size_t)(col0 + r0) * D_DIM + q0 * 8;
    size_t boff1 = (size_t)(col0 + r1) * D_DIM + q1 * 8;

    // fragment base element offsets: (r>>3)*256 + q*64 + (r&7)*8
    int am0 = wr + m;
    int bn0 = wc + m;
    int offA = ((am0 >> 3) << 8) + (q << 6) + ((am0 & 7) << 3);
    int offB = ((bn0 >> 3) << 8) + (q << 6) + ((bn0 & 7) << 3);

    floatx4 acc[4][4];
    #pragma unroll
    for (int i = 0; i < 4; i++)
        #pragma unroll
        for (int j = 0; j < 4; j++)
            acc[i][j] = (floatx4){0.f, 0.f, 0.f, 0.f};

    for (int k0 = 0; k0 < D_DIM; k0 += GBK) {
        gload16(Ahi + aoff0 + k0, &sA[0][p0 * 8]);
        gload16(Ahi + aoff1 + k0, &sA[0][p1 * 8]);
        gload16(Alo + aoff0 + k0, &sA[1][p0 * 8]);
        gload16(Alo + aoff1 + k0, &sA[1][p1 * 8]);
        gload16(Bhi + boff0 + k0, &sB[0][p0 * 8]);
        gload16(Bhi + boff1 + k0, &sB[0][p1 * 8]);
        gload16(Blo + boff0 + k0, &sB[1][p0 * 8]);
        gload16(Blo + boff1 + k0, &sB[1][p1 * 8]);
        __syncthreads();

        short8 fah[4], fal[4];
        #pragma unroll
        for (int i = 0; i < 4; i++) {
            fah[i] = *(const short8*)&sA[0][offA + i * 512];
            fal[i] = *(const short8*)&sA[1][offA + i * 512];
        }
        #pragma unroll
        for (int j = 0; j < 4; j++) {
            short8 fbh = *(const short8*)&sB[0][offB + j * 512];
            short8 fbl = *(const short8*)&sB[1][offB + j * 512];
            #pragma unroll
            for (int i = 0; i < 4; i++) {
                acc[i][j] = __builtin_amdgcn_mfma_f32_16x16x32_bf16(fah[i], fbh, acc[i][j], 0, 0, 0);
                acc[i][j] = __builtin_amdgcn_mfma_f32_16x16x32_bf16(fal[i], fbh, acc[i][j], 0, 0, 0);
                acc[i][j] = __builtin_amdgcn_mfma_f32_16x16x32_bf16(fah[i], fbl, acc[i][j], 0, 0, 0);
            }
        }
        __syncthreads();
    }

    #pragma unroll
    for (int i = 0; i < 4; i++) {
        #pragma unroll
        for (int r = 0; r < 4; r++) {
            int grow = row0 + wr + i * 16 + q * 4 + r;
            float* dst = latent + (size_t)grow * H_DIM + col0 + wc + m;
            #pragma unroll
            for (int j = 0; j < 4; j++) {
                float cosv = acc[i][j][r];
                float sim = 2.f - sqrtf(fmaxf(2.f - 2.f * cosv, 0.f));
                dst[j * 16] = sim;
            }
        }
    }
}

// ---------------------------------------------------------------------------
// per-row histogram of |sim| -> bin containing the 33rd largest
__global__ void hist_kernel(const float* __restrict__ latent,
                            int* __restrict__ rowbin)
{
    int row = blockIdx.x;
    int tid = threadIdx.x;
    int wave = tid >> 6, lane = tid & 63;
    __shared__ unsigned h4[4][BINS];
    for (int k = tid; k < 4 * BINS; k += 256) ((unsigned*)h4)[k] = 0;
    __syncthreads();
    const float4* v4 = (const float4*)(latent + (size_t)row * H_DIM);
    for (int i = tid; i < H_DIM / 4; i += 256) {
        float4 x = v4[i];
        float e[4] = {x.x, x.y, x.z, x.w};
        #pragma unroll
        for (int t = 0; t < 4; t++) {
            unsigned u = __float_as_uint(e[t]) & 0x7FFFFFFFu;
            int k = (int)(u >> 16) - BIN_OFF;
            k = max(0, min(BINS - 1, k));
            atomicAdd(&h4[wave][k], 1u);
        }
    }
    __syncthreads();
    for (int k = tid; k < BINS; k += 256)
        h4[0][k] += h4[1][k] + h4[2][k] + h4[3][k];
    __syncthreads();
    if (wave == 0) {
        int topb = BINS - 1 - lane * 16;      // highest bin of this lane's group
        unsigned s16 = 0;
        #pragma unroll
        for (int t = 0; t < 16; t++) s16 += h4[0][topb - t];
        unsigned c = s16;
        #pragma unroll
        for (int o = 1; o < 64; o <<= 1) {
            unsigned xx = __shfl_up(c, o);
            if (lane >= o) c += xx;
        }
        bool hit = (c >= (unsigned)KSEL);
        unsigned long long mk = __ballot(hit);
        int L = __ffsll((unsigned long long)mk) - 1;
        if (lane == L) {
            unsigned cc = c - s16;
            int B = 0;
            for (int t = 0; t < 16; t++) {
                cc += h4[0][topb - t];
                if (cc >= (unsigned)KSEL) { B = topb - t; break; }
            }
            rowbin[row] = B;
        }
    }
}

// ---------------------------------------------------------------------------
// collect candidates (key >= B), zero the rest, rank candidates exactly on
// approx values, classify with +-MARGIN around v* (33rd largest approx).
__global__ void select2_kernel(float* __restrict__ latent,
                               const int* __restrict__ rowbin,
                               int* __restrict__ sel_cnt,
                               int* __restrict__ sel_idx,
                               float* __restrict__ sel_val,
                               int* __restrict__ amb_cnt,
                               int* __restrict__ amb_idx)
{
    int row = blockIdx.x;
    int tid = threadIdx.x;
    int B = rowbin[row];
    float* v = latent + (size_t)row * H_DIM;
    __shared__ unsigned ca[CAND_CAP];
    __shared__ float    cf[CAND_CAP];
    __shared__ int      ci[CAND_CAP];
    __shared__ int scnt, svstar, skept, samb;
    if (tid == 0) { scnt = 0; svstar = 0x7FFFFFFF; skept = 0; samb = 0; }
    __syncthreads();

    float4* v4 = (float4*)v;
    for (int i = tid; i < H_DIM / 4; i += 256) {
        float4 x = v4[i];
        float e[4] = {x.x, x.y, x.z, x.w};
        unsigned u[4]; int k[4];
        #pragma unroll
        for (int t = 0; t < 4; t++) {
            u[t] = __float_as_uint(e[t]) & 0x7FFFFFFFu;
            k[t] = max(0, min(BINS - 1, (int)(u[t] >> 16) - BIN_OFF));
        }
        if (k[0] < B && k[1] < B && k[2] < B && k[3] < B) {
            v4[i] = make_float4(0.f, 0.f, 0.f, 0.f);
        } else {
            #pragma unroll
            for (int t = 0; t < 4; t++) {
                if (k[t] < B) {
                    v[4 * i + t] = 0.f;
                } else {
                    int c = atomicAdd(&scnt, 1);
                    if (c < CAND_CAP) { ca[c] = u[t]; cf[c] = e[t]; ci[c] = 4 * i + t; }
                    else v[4 * i + t] = 0.f;
                }
            }
        }
    }
    __syncthreads();
    int C = min(scnt, CAND_CAP);
    for (int c = tid; c < C; c += 256) {
        unsigned u = ca[c];
        int gt = 0;
        for (int j = 0; j < C; j++) gt += (ca[j] > u) ? 1 : 0;
        if (gt <= TOPK) atomicMin(&svstar, (int)u);
    }
    __syncthreads();
    float vs = __uint_as_float((unsigned)svstar);
    for (int c = tid; c < C; c += 256) {
        float a = __uint_as_float(ca[c]);
        float f = cf[c];
        int idx = ci[c];
        if (a > vs + MARGIN) {
            int s = atomicAdd(&skept, 1);
            sel_idx[row * SEL_CAP + s] = idx;
            sel_val[row * SEL_CAP + s] = f;
            // latent[idx] already holds f
        } else if (a < vs - MARGIN) {
            v[idx] = 0.f;
        } else {
            int s = atomicAdd(&samb, 1);
            if (s < AMB_CAP) amb_idx[row * AMB_CAP + s] = idx;
            else v[idx] = 0.f;
        }
    }
    __syncthreads();
    if (tid == 0) { sel_cnt[row] = skept; amb_cnt[row] = min(samb, AMB_CAP); }
}

// ---------------------------------------------------------------------------
// exact fp32 recompute for ambiguous entries; tie-aware np-exact top-off
__global__ void refine_kernel(const float* __restrict__ embv,
                              const float* __restrict__ embt,
                              const float* __restrict__ enc,
                              const float* __restrict__ invA,
                              const float* __restrict__ invB,
                              float* __restrict__ latent,
                              int* __restrict__ sel_cnt,
                              int* __restrict__ sel_idx,
                              float* __restrict__ sel_val,
                              const int* __restrict__ amb_cnt,
                              const int* __restrict__ amb_idx)
{
    int row = blockIdx.x;
    int s = amb_cnt[row];
    if (s == 0) return;
    int tid = threadIdx.x;
    int m = sel_cnt[row];
    int need = TOPK - m;
    float* v = latent + (size_t)row * H_DIM;
    if (need <= 0) {
        for (int a = tid; a < s; a += 256) v[amb_idx[row * AMB_CAP + a]] = 0.f;
        return;
    }
    __shared__ float ex[AMB_CAP];
    __shared__ int evs, kc;
    const float* src = (row < N_ROWS) ? embv + (size_t)row * D_DIM
                                      : embt + (size_t)(row - N_ROWS) * D_DIM;
    float ia = invA[row];
    int wave = tid >> 6, lane = tid & 63;
    for (int a = wave; a < s; a += 4) {
        int h = amb_idx[row * AMB_CAP + a];
        const float* w = enc + (size_t)h * D_DIM;
        float d = 0.f;
        for (int t = lane; t < D_DIM; t += 64) d += src[t] * w[t];
        #pragma unroll
        for (int o = 32; o > 0; o >>= 1) d += __shfl_down(d, o);
        if (lane == 0) {
            float cosv = d * ia * invB[h];
            ex[a] = 2.f - sqrtf(fmaxf(2.f - 2.f * cosv, 0.f));
        }
    }
    if (tid == 0) { evs = 0x7FFFFFFF; kc = 0; }
    __syncthreads();
    if (tid < s) {
        float mya = fabsf(ex[tid]);
        int gt = 0;
        for (int j = 0; j < s; j++) gt += (fabsf(ex[j]) > mya) ? 1 : 0;
        if (gt <= need) atomicMin(&evs, __float_as_int(mya));
    }
    __syncthreads();
    float ep = __int_as_float(evs);
    if (tid < s) {
        int idx = amb_idx[row * AMB_CAP + tid];
        float e = ex[tid];
        if (fabsf(e) > ep) {
            int sl = atomicAdd(&kc, 1);
            v[idx] = e;
            sel_idx[row * SEL_CAP + m + sl] = idx;
            sel_val[row * SEL_CAP + m + sl] = e;
        } else {
            v[idx] = 0.f;
        }
    }
    __syncthreads();
    if (tid == 0) sel_cnt[row] = m + kc;
}

// ---------------------------------------------------------------------------
__global__ void transpose_kernel(const float* __restrict__ Wv,
                                 const float* __restrict__ Wt,
                                 float* __restrict__ WvT,
                                 float* __restrict__ WtT)
{
    int z = blockIdx.z;
    const float* W = z ? Wt : Wv;
    float* WT = z ? WtT : WvT;
    __shared__ float tile[32][33];
    int tx = threadIdx.x & 31;
    int ty = threadIdx.x >> 5;
    int h0 = blockIdx.x * 32;
    int d0 = blockIdx.y * 32;
    #pragma unroll
    for (int t = 0; t < 4; t++)
        tile[ty + t * 8][tx] = W[(size_t)(d0 + ty + t * 8) * H_DIM + h0 + tx];
    __syncthreads();
    #pragma unroll
    for (int t = 0; t < 4; t++)
        WT[(size_t)(h0 + ty + t * 8) * D_DIM + d0 + tx] = tile[tx][ty + t * 8];
}

// ---------------------------------------------------------------------------
__global__ void recon_kernel(const float* __restrict__ Wv_,
                             const float* __restrict__ Wt_,
                             const float* __restrict__ bv,
                             const float* __restrict__ bt,
                             const int* __restrict__ sel_cnt,
                             const int* __restrict__ sel_idx,
                             const float* __restrict__ sel_val,
                             long sh, long sd,
                             float* __restrict__ out)
{
    int n = blockIdx.x;
    int z = blockIdx.y;
    int row = z * N_ROWS + n;
    const float* W = z ? Wt_ : Wv_;
    const float* bias = z ? bt : bv;
    float* o = out + (size_t)z * N_ROWS * D_DIM + (size_t)n * D_DIM;

    __shared__ int s_idx[SEL_CAP];
    __shared__ float s_val[SEL_CAP];
    __shared__ int s_cnt;
    int tid = threadIdx.x;
    if (tid == 0) s_cnt = sel_cnt[row];
    __syncthreads();
    int cnt = s_cnt;
    if (tid < cnt) {
        s_idx[tid] = sel_idx[(size_t)row * SEL_CAP + tid];
        s_val[tid] = sel_val[(size_t)row * SEL_CAP + tid];
    }
    __syncthreads();

    for (int d = tid; d < D_DIM; d += 256) {
        float acc = bias[d];
        for (int j = 0; j < cnt; j++)
            acc += s_val[j] * W[(size_t)s_idx[j] * sh + (size_t)d * sd];
        o[d] = acc;
    }
}

// ============================ LEGACY FALLBACK ==============================
__global__ void row_invnorm_kernel(const float* __restrict__ x,
                                   float* __restrict__ inv, int rows) {
    int row = blockIdx.x * 4 + (threadIdx.x >> 6);
    int lane = threadIdx.x & 63;
    if (row >= rows) return;
    const float4* p = reinterpret_cast<const float4*>(x + (size_t)row * D_DIM);
    float ss = 0.f;
    #pragma unroll
    for (int i = 0; i < 3; i++) {
        float4 v = p[lane + i * 64];
        ss += v.x * v.x + v.y * v.y + v.z * v.z + v.w * v.w;
    }
    #pragma unroll
    for (int off = 32; off > 0; off >>= 1) ss += __shfl_down(ss, off);
    if (lane == 0) inv[row] = 1.f / fmaxf(sqrtf(ss), 1e-12f);
}

#define BM 128
#define BN 128
#define BK 16
__global__ __launch_bounds__(256)
void gemm_sim_kernel(const float* __restrict__ embv,
                     const float* __restrict__ embt,
                     const float* __restrict__ enc,
                     const float* __restrict__ inv_emb,
                     const float* __restrict__ inv_enc,
                     float* __restrict__ latent)
{
    int z = blockIdx.z;
    const float* A = z ? embt : embv;
    const float* invA = inv_emb + z * N_ROWS;
    float* C = latent + (size_t)z * N_ROWS * H_DIM;
    __shared__ float As[BK][BM + 4];
    __shared__ float Bs[BK][BN + 4];
    int tid = threadIdx.x;
    int tx = tid & 15, ty = tid >> 4;
    int row0 = blockIdx.y * BM, col0 = blockIdx.x * BN;
    float acc[8][8];
    #pragma unroll
    for (int i = 0; i < 8; i++)
        #pragma unroll
        for (int j = 0; j < 8; j++) acc[i][j] = 0.f;
    for (int k0 = 0; k0 < D_DIM; k0 += BK) {
        #pragma unroll
        for (int t = 0; t < 2; t++) {
            int idx = t * 256 + tid;
            int r = idx >> 2, c4 = idx & 3;
            float4 va = *reinterpret_cast<const float4*>(
                A + (size_t)(row0 + r) * D_DIM + k0 + c4 * 4);
            As[c4 * 4 + 0][r] = va.x; As[c4 * 4 + 1][r] = va.y;
            As[c4 * 4 + 2][r] = va.z; As[c4 * 4 + 3][r] = va.w;
            float4 vb = *reinterpret_cast<const float4*>(
                enc + (size_t)(col0 + r) * D_DIM + k0 + c4 * 4);
            Bs[c4 * 4 + 0][r] = vb.x; Bs[c4 * 4 + 1][r] = vb.y;
            Bs[c4 * 4 + 2][r] = vb.z; Bs[c4 * 4 + 3][r] = vb.w;
        }
        __syncthreads();
        #pragma unroll
        for (int kk = 0; kk < BK; kk++) {
            float a[8], b[8];
            *reinterpret_cast<float4*>(&a[0]) = *reinterpret_cast<const float4*>(&As[kk][ty * 8]);
            *reinterpret_cast<float4*>(&a[4]) = *reinterpret_cast<const float4*>(&As[kk][ty * 8 + 4]);
            *reinterpret_cast<float4*>(&b[0]) = *reinterpret_cast<const float4*>(&Bs[kk][tx * 8]);
            *reinterpret_cast<float4*>(&b[4]) = *reinterpret_cast<const float4*>(&Bs[kk][tx * 8 + 4]);
            #pragma unroll
            for (int i = 0; i < 8; i++)
                #pragma unroll
                for (int j = 0; j < 8; j++)
                    acc[i][j] = fmaf(a[i], b[j], acc[i][j]);
        }
        __syncthreads();
    }
    #pragma unroll
    for (int i = 0; i < 8; i++) {
        int n = row0 + ty * 8 + i;
        float sa = invA[n];
        float* Crow = C + (size_t)n * H_DIM + col0 + tx * 8;
        float tmp[8];
        #pragma unroll
        for (int j = 0; j < 8; j++) {
            float cosv = acc[i][j] * sa * inv_enc[col0 + tx * 8 + j];
            tmp[j] = 2.f - sqrtf(fmaxf(2.f - 2.f * cosv, 0.f));
        }
        float4 o0 = {tmp[0], tmp[1], tmp[2], tmp[3]};
        float4 o1 = {tmp[4], tmp[5], tmp[6], tmp[7]};
        *reinterpret_cast<float4*>(Crow) = o0;
        *reinterpret_cast<float4*>(Crow + 4) = o1;
    }
}

__global__ void select_kernel(float* __restrict__ latent,
                              const int* __restrict__ topk_p,
                              int* __restrict__ sel_cnt,
                              int* __restrict__ sel_idx,
                              float* __restrict__ sel_val)
{
    int row = blockIdx.x;
    float* v = latent + (size_t)row * H_DIM;
    int tid = threadIdx.x;
    __shared__ unsigned hist[256];
    __shared__ unsigned s_prefix;
    __shared__ int s_k;
    __shared__ int s_cnt;
    int k = topk_p[0] + 1;
    unsigned prefix = 0;
    for (int shift = 24; shift >= 0; shift -= 8) {
        hist[tid] = 0;
        __syncthreads();
        unsigned pmask = (shift == 24) ? 0u : (0xFFFFFFFFu << (shift + 8));
        for (int i = tid; i < H_DIM; i += 256) {
            unsigned u = __float_as_uint(v[i]) & 0x7FFFFFFFu;
            if ((u & pmask) == prefix)
                atomicAdd(&hist[(u >> shift) & 255u], 1u);
        }
        __syncthreads();
        if (tid == 0) {
            int c = 0, b = 255;
            for (; b >= 0; b--) {
                c += (int)hist[b];
                if (c >= k) break;
            }
            if (b < 0) b = 0;
            s_prefix = prefix | ((unsigned)b << shift);
            s_k = k - (c - (int)hist[b]);
        }
        __syncthreads();
        prefix = s_prefix;
        k = s_k;
        __syncthreads();
    }
    float thres = __uint_as_float(prefix);
    if (tid == 0) s_cnt = 0;
    __syncthreads();
    for (int i = tid; i < H_DIM; i += 256) {
        float x = v[i];
        bool keep = (fabsf(x) > thres);
        v[i] = keep ? x : 0.f;
        if (keep) {
            int slot = atomicAdd(&s_cnt, 1);
            if (slot < SEL_CAP) {
                sel_idx[(size_t)row * SEL_CAP + slot] = i;
                sel_val[(size_t)row * SEL_CAP + slot] = x;
            }
        }
    }
    __syncthreads();
    if (tid == 0) sel_cnt[row] = (s_cnt > SEL_CAP) ? SEL_CAP : s_cnt;
}

// ---------------------------------------------------------------------------
extern "C" void kernel_launch(void* const* d_in, const int* in_sizes, int n_in,
                              void* d_out, int out_size, void* d_ws, size_t ws_size,
                              hipStream_t stream) {
    const float* embv = (const float*)d_in[0];
    const float* embt = (const float*)d_in[1];
    const float* enc  = (const float*)d_in[2];
    const float* Wv   = (const float*)d_in[3];
    const float* bv   = (const float*)d_in[4];
    const float* Wt   = (const float*)d_in[5];
    const float* bt   = (const float*)d_in[6];
    const int* topk   = (const int*)d_in[7];
    float* out = (float*)d_out;

    float* recon_out = out;                              // [2][N][D]
    float* latent = out + (size_t)2 * N_ROWS * D_DIM;    // [2][N][H]

    char* ws = (char*)d_ws;
    size_t off = 0;
    float* invA = (float*)(ws + off);            off += (size_t)M_TOT * 4;
    float* invB = (float*)(ws + off);            off += (size_t)H_DIM * 4;
    int*   rowbin = (int*)(ws + off);            off += (size_t)M_TOT * 4;
    int*   sel_cnt = (int*)(ws + off);           off += (size_t)M_TOT * 4;
    int*   amb_cnt = (int*)(ws + off);           off += (size_t)M_TOT * 4;
    int*   sel_idx = (int*)(ws + off);           off += (size_t)M_TOT * SEL_CAP * 4;
    float* sel_val = (float*)(ws + off);         off += (size_t)M_TOT * SEL_CAP * 4;
    int*   amb_idx = (int*)(ws + off);           off += (size_t)M_TOT * AMB_CAP * 4;
    unsigned short* Ahi = (unsigned short*)(ws + off); off += (size_t)M_TOT * D_DIM * 2;
    unsigned short* Alo = (unsigned short*)(ws + off); off += (size_t)M_TOT * D_DIM * 2;
    unsigned short* Bhi = (unsigned short*)(ws + off); off += (size_t)H_DIM * D_DIM * 2;
    unsigned short* Blo = (unsigned short*)(ws + off); off += (size_t)H_DIM * D_DIM * 2;
    size_t core_need = off;
    float* WvT = (float*)(ws + off);
    float* WtT = WvT + (size_t)D_DIM * H_DIM;
    size_t full_need = off + (size_t)2 * D_DIM * H_DIM * 4;

    if (ws_size >= core_need) {
        bool use_T = ws_size >= full_need;
        split_kernel<<<N_ROWS, 256, 0, stream>>>(embv, Ahi, Alo, invA);
        split_kernel<<<N_ROWS, 256, 0, stream>>>(embt,
            Ahi + (size_t)N_ROWS * D_DIM, Alo + (size_t)N_ROWS * D_DIM, invA + N_ROWS);
        split_kernel<<<H_DIM, 256, 0, stream>>>(enc, Bhi, Blo, invB);

        gemm_mfma_kernel<<<dim3(H_DIM / 128, M_TOT / 128), 256, 0, stream>>>(
            Ahi, Alo, Bhi, Blo, latent);

        hist_kernel<<<M_TOT, 256, 0, stream>>>(latent, rowbin);
        select2_kernel<<<M_TOT, 256, 0, stream>>>(latent, rowbin,
            sel_cnt, sel_idx, sel_val, amb_cnt, amb_idx);
        refine_kernel<<<M_TOT, 256, 0, stream>>>(embv, embt, enc, invA, invB,
            latent, sel_cnt, sel_idx, sel_val, amb_cnt, amb_idx);

        if (use_T) {
            transpose_kernel<<<dim3(H_DIM / 32, D_DIM / 32, 2), 256, 0, stream>>>(
                Wv, Wt, WvT, WtT);
            recon_kernel<<<dim3(N_ROWS, 2), 256, 0, stream>>>(
                WvT, WtT, bv, bt, sel_cnt, sel_idx, sel_val, (long)D_DIM, 1L, recon_out);
        } else {
            recon_kernel<<<dim3(N_ROWS, 2), 256, 0, stream>>>(
                Wv, Wt, bv, bt, sel_cnt, sel_idx, sel_val, 1L, (long)H_DIM, recon_out);
        }
    } else {
        // legacy all-fp32 path (small workspace)
        size_t o2 = 0;
        float* inv_enc = (float*)(ws + o2); o2 += (size_t)H_DIM * 4;
        float* inv_emb = (float*)(ws + o2); o2 += (size_t)2 * N_ROWS * 4;
        int*   l_cnt = (int*)(ws + o2);     o2 += (size_t)2 * N_ROWS * 4;
        int*   l_idx = (int*)(ws + o2);     o2 += (size_t)2 * N_ROWS * SEL_CAP * 4;
        float* l_val = (float*)(ws + o2);   o2 += (size_t)2 * N_ROWS * SEL_CAP * 4;
        row_invnorm_kernel<<<H_DIM / 4, 256, 0, stream>>>(enc, inv_enc, H_DIM);
        row_invnorm_kernel<<<N_ROWS / 4, 256, 0, stream>>>(embv, inv_emb, N_ROWS);
        row_invnorm_kernel<<<N_ROWS / 4, 256, 0, stream>>>(embt, inv_emb + N_ROWS, N_ROWS);
        dim3 g(H_DIM / BN, N_ROWS / BM, 2);
        gemm_sim_kernel<<<g, 256, 0, stream>>>(embv, embt, enc, inv_emb, inv_enc, latent);
        select_kernel<<<2 * N_ROWS, 256, 0, stream>>>(latent, topk, l_cnt, l_idx, l_val);
        recon_kernel<<<dim3(N_ROWS, 2), 256, 0, stream>>>(
            Wv, Wt, bv, bt, l_cnt, l_idx, l_val, 1L, (long)H_DIM, recon_out);
    }
}

// Round 3
// 1716.466 us; speedup vs baseline: 2.3691x; 1.0858x over previous
//
#include <hip/hip_runtime.h>
#include <math.h>

// ============================================================================
// VL_SAE: N=4096, D=768, H=16384, topk=32
// Round 3:
//   - 2-product bf16 split GEMM: (Ahi+Alo)*Bhi. Dropped-term error sigma
//     ~3.5e-5 in cos; MARGIN=1e-3 (28 sigma) + exact-fp32 refine covers
//     all top-k boundary decisions. 33% less MFMA, 25% less staging,
//     LDS 24KB -> launch_bounds(256,4).
//   - Merged select (replaces hist+select2): per-thread max over 64 elems;
//     33rd largest of the 256 thread-maxes is a PROVEN lower bound on the
//     row's 33rd-largest |sim| (top-33 elements occupy <=33 threads).
//     Row cached fp16 in LDS so pass-2 is HBM-free. No LDS atomics hist.
//   - refine: exact fp32 dots for +-MARGIN-ambiguous entries, np-exact
//     tie-aware top-off (unchanged from round 2, proven correct).
// ============================================================================

#define N_ROWS 4096
#define D_DIM  768
#define H_DIM  16384
#define M_TOT  8192
#define TOPK   32
#define MARGIN 1e-3f
#define SEL_CAP 40
#define AMB_CAP 64
#define CAP2   512

typedef __attribute__((ext_vector_type(8))) short short8;
typedef __attribute__((ext_vector_type(4))) float floatx4;

__device__ inline unsigned short bf16_rne(float f) {
    unsigned u = __float_as_uint(f);
    unsigned r = u + 0x7fffu + ((u >> 16) & 1u);
    return (unsigned short)(r >> 16);
}

__device__ inline void gload16(const unsigned short* g, unsigned short* l) {
    __builtin_amdgcn_global_load_lds(
        (const __attribute__((address_space(1))) void*)g,
        (__attribute__((address_space(3))) void*)l, 16, 0, 0);
}

// ---------------------------------------------------------------------------
// normalize rows of embv/embt/enc; emb -> bf16 hi+lo, enc -> bf16 hi only
__global__ void split_all_kernel(const float* __restrict__ embv,
                                 const float* __restrict__ embt,
                                 const float* __restrict__ enc,
                                 unsigned short* __restrict__ Ahi,
                                 unsigned short* __restrict__ Alo,
                                 unsigned short* __restrict__ Bh,
                                 float* __restrict__ invA,
                                 float* __restrict__ invB)
{
    int row = blockIdx.x;                  // 0..2N+H-1
    int tid = threadIdx.x;
    const float* src;
    unsigned short *hi, *lo;
    float* invp;
    if (row < N_ROWS) {
        src = embv + (size_t)row * D_DIM;
        hi = Ahi + (size_t)row * D_DIM; lo = Alo + (size_t)row * D_DIM;
        invp = invA + row;
    } else if (row < 2 * N_ROWS) {
        int r = row - N_ROWS;
        src = embt + (size_t)r * D_DIM;
        hi = Ahi + (size_t)row * D_DIM; lo = Alo + (size_t)row * D_DIM;
        invp = invA + row;
    } else {
        int r = row - 2 * N_ROWS;
        src = enc + (size_t)r * D_DIM;
        hi = Bh + (size_t)r * D_DIM; lo = nullptr;
        invp = invB + r;
    }
    __shared__ float red[4];
    const float4* s4 = reinterpret_cast<const float4*>(src);
    float4 v = make_float4(0.f, 0.f, 0.f, 0.f);
    float ss = 0.f;
    if (tid < 192) {
        v = s4[tid];
        ss = v.x * v.x + v.y * v.y + v.z * v.z + v.w * v.w;
    }
    #pragma unroll
    for (int o = 32; o > 0; o >>= 1) ss += __shfl_down(ss, o);
    int wave = tid >> 6, lane = tid & 63;
    if (lane == 0) red[wave] = ss;
    __syncthreads();
    if (tid == 0) {
        float tot = red[0] + red[1] + red[2];
        red[0] = 1.f / fmaxf(sqrtf(tot), 1e-12f);
    }
    __syncthreads();
    float inv = red[0];
    if (tid == 0) *invp = inv;
    if (tid < 192) {
        float x[4] = {v.x * inv, v.y * inv, v.z * inv, v.w * inv};
        unsigned short hh[4], ll[4];
        #pragma unroll
        for (int t = 0; t < 4; t++) {
            hh[t] = bf16_rne(x[t]);
            float hf = __uint_as_float((unsigned)hh[t] << 16);
            ll[t] = bf16_rne(x[t] - hf);
        }
        ushort4 h4; h4.x = hh[0]; h4.y = hh[1]; h4.z = hh[2]; h4.w = hh[3];
        *reinterpret_cast<ushort4*>(hi + tid * 4) = h4;
        if (lo) {
            ushort4 l4; l4.x = ll[0]; l4.y = ll[1]; l4.z = ll[2]; l4.w = ll[3];
            *reinterpret_cast<ushort4*>(lo + tid * 4) = l4;
        }
    }
}

// ---------------------------------------------------------------------------
// 2-product split GEMM: cos = (Ahi+Alo) . Bh  (inputs pre-normalized)
#define GBK 32

__global__ __launch_bounds__(256, 4)
void gemm_mfma_kernel(const unsigned short* __restrict__ Ahi,
                      const unsigned short* __restrict__ Alo,
                      const unsigned short* __restrict__ Bh,
                      float* __restrict__ latent)
{
    __shared__ unsigned short sA[2][128 * GBK];
    __shared__ unsigned short sB[128 * GBK];

    int tid = threadIdx.x;
    int lane = tid & 63;
    int wave = tid >> 6;
    int wr = (wave >> 1) * 64;
    int wc = (wave & 1) * 64;
    int m = lane & 15;
    int q = lane >> 4;

    int row0 = blockIdx.y * 128;
    int col0 = blockIdx.x * 128;

    int p0 = tid, p1 = tid + 256;
    int r0 = ((p0 >> 5) << 3) | (p0 & 7), q0 = (p0 >> 3) & 3;
    int r1 = ((p1 >> 5) << 3) | (p1 & 7), q1 = (p1 >> 3) & 3;
    size_t aoff0 = (size_t)(row0 + r0) * D_DIM + q0 * 8;
    size_t aoff1 = (size_t)(row0 + r1) * D_DIM + q1 * 8;
    size_t boff0 = (size_t)(col0 + r0) * D_DIM + q0 * 8;
    size_t boff1 = (size_t)(col0 + r1) * D_DIM + q1 * 8;

    int am0 = wr + m;
    int bn0 = wc + m;
    int offA = ((am0 >> 3) << 8) + (q << 6) + ((am0 & 7) << 3);
    int offB = ((bn0 >> 3) << 8) + (q << 6) + ((bn0 & 7) << 3);

    floatx4 acc[4][4];
    #pragma unroll
    for (int i = 0; i < 4; i++)
        #pragma unroll
        for (int j = 0; j < 4; j++)
            acc[i][j] = (floatx4){0.f, 0.f, 0.f, 0.f};

    for (int k0 = 0; k0 < D_DIM; k0 += GBK) {
        gload16(Ahi + aoff0 + k0, &sA[0][p0 * 8]);
        gload16(Ahi + aoff1 + k0, &sA[0][p1 * 8]);
        gload16(Alo + aoff0 + k0, &sA[1][p0 * 8]);
        gload16(Alo + aoff1 + k0, &sA[1][p1 * 8]);
        gload16(Bh + boff0 + k0, &sB[p0 * 8]);
        gload16(Bh + boff1 + k0, &sB[p1 * 8]);
        __syncthreads();

        short8 fah[4], fal[4];
        #pragma unroll
        for (int i = 0; i < 4; i++) {
            fah[i] = *(const short8*)&sA[0][offA + i * 512];
            fal[i] = *(const short8*)&sA[1][offA + i * 512];
        }
        #pragma unroll
        for (int j = 0; j < 4; j++) {
            short8 fb = *(const short8*)&sB[offB + j * 512];
            #pragma unroll
            for (int i = 0; i < 4; i++) {
                acc[i][j] = __builtin_amdgcn_mfma_f32_16x16x32_bf16(fah[i], fb, acc[i][j], 0, 0, 0);
                acc[i][j] = __builtin_amdgcn_mfma_f32_16x16x32_bf16(fal[i], fb, acc[i][j], 0, 0, 0);
            }
        }
        __syncthreads();
    }

    #pragma unroll
    for (int i = 0; i < 4; i++) {
        #pragma unroll
        for (int r = 0; r < 4; r++) {
            int grow = row0 + wr + i * 16 + q * 4 + r;
            float* dst = latent + (size_t)grow * H_DIM + col0 + wc + m;
            #pragma unroll
            for (int j = 0; j < 4; j++) {
                float cosv = acc[i][j][r];
                float sim = 2.f - sqrtf(fmaxf(2.f - 2.f * cosv, 0.f));
                dst[j * 16] = sim;
            }
        }
    }
}

// ---------------------------------------------------------------------------
// Merged select: thread-max lower bound -> candidates -> v* -> classify.
// Row cached as fp16 in LDS; pass 2 never re-reads HBM.
__global__ __launch_bounds__(256)
void select_kernel(float* __restrict__ latent,
                   int* __restrict__ sel_cnt,
                   int* __restrict__ sel_idx,
                   float* __restrict__ sel_val,
                   int* __restrict__ amb_cnt,
                   int* __restrict__ amb_idx)
{
    int row = blockIdx.x;
    int tid = threadIdx.x;
    float* v = latent + (size_t)row * H_DIM;
    const float4* v4 = (const float4*)v;
    float4* vw = (float4*)v;

    __shared__ _Float16 hbuf[H_DIM];       // 32 KB |sim| cache
    __shared__ float smax[256];
    __shared__ float sca[CAP2];            // candidate fp32 value (signed)
    __shared__ int   sci[CAP2];            // candidate index
    __shared__ float sT;
    __shared__ int scnt, svstar, skept, samb;

    // pass 1: per-thread max of 64 strided elements; cache |x| as fp16
    float mx = -1.f;
    #pragma unroll 4
    for (int k = 0; k < 16; k++) {
        int i = tid + 256 * k;
        float4 x = v4[i];
        float a0 = fabsf(x.x), a1 = fabsf(x.y), a2 = fabsf(x.z), a3 = fabsf(x.w);
        hbuf[4 * i + 0] = (_Float16)a0;
        hbuf[4 * i + 1] = (_Float16)a1;
        hbuf[4 * i + 2] = (_Float16)a2;
        hbuf[4 * i + 3] = (_Float16)a3;
        mx = fmaxf(mx, fmaxf(fmaxf(a0, a1), fmaxf(a2, a3)));
    }
    smax[tid] = mx;
    if (tid == 0) { scnt = 0; svstar = 0x7FFFFFFF; skept = 0; samb = 0; }
    __syncthreads();

    // 33rd largest thread-max (tie-broken) = lower bound T <= row's 33rd |sim|
    int gt = 0;
    for (int j = 0; j < 256; j++) {
        float mj = smax[j];
        gt += (mj > mx || (mj == mx && j < tid)) ? 1 : 0;
    }
    if (gt == 32) sT = mx;
    __syncthreads();
    float Tm = sT - MARGIN;

    // pass 2: collect candidates (|a| >= T - MARGIN), zero-write the row.
    // Owner thread reads exact fp32 from global BEFORE overwriting.
    #pragma unroll 4
    for (int k = 0; k < 16; k++) {
        int i = tid + 256 * k;
        float a[4];
        a[0] = (float)hbuf[4 * i + 0]; a[1] = (float)hbuf[4 * i + 1];
        a[2] = (float)hbuf[4 * i + 2]; a[3] = (float)hbuf[4 * i + 3];
        bool any = (a[0] >= Tm) | (a[1] >= Tm) | (a[2] >= Tm) | (a[3] >= Tm);
        if (any) {
            #pragma unroll
            for (int t = 0; t < 4; t++) {
                if (a[t] >= Tm) {
                    int c = atomicAdd(&scnt, 1);
                    if (c < CAP2) { sci[c] = 4 * i + t; sca[c] = v[4 * i + t]; }
                }
            }
        }
        vw[i] = make_float4(0.f, 0.f, 0.f, 0.f);
    }
    __syncthreads();

    // v* = 33rd largest |candidate| (tie-broken by slot)
    int C = min(scnt, CAP2);
    for (int c = tid; c < C; c += 256) {
        float a = fabsf(sca[c]);
        int g = 0;
        for (int j = 0; j < C; j++) {
            float aj = fabsf(sca[j]);
            g += (aj > a || (aj == a && j < c)) ? 1 : 0;
        }
        if (g <= TOPK) atomicMin(&svstar, __float_as_int(a));
    }
    __syncthreads();
    float vs = __int_as_float(svstar);

    // classify: certain-keep / certain-drop / ambiguous
    for (int c = tid; c < C; c += 256) {
        float f = sca[c];
        float a = fabsf(f);
        int idx = sci[c];
        if (a > vs + MARGIN) {
            int s = atomicAdd(&skept, 1);
            sel_idx[(size_t)row * SEL_CAP + s] = idx;
            sel_val[(size_t)row * SEL_CAP + s] = f;
            v[idx] = f;
        } else if (a >= vs - MARGIN) {
            int s = atomicAdd(&samb, 1);
            if (s < AMB_CAP) amb_idx[(size_t)row * AMB_CAP + s] = idx;
            // stays zero unless refine restores
        }
        // else: certain drop, already zero
    }
    __syncthreads();
    if (tid == 0) { sel_cnt[row] = skept; amb_cnt[row] = min(samb, AMB_CAP); }
}

// ---------------------------------------------------------------------------
// exact fp32 recompute for ambiguous entries; tie-aware np-exact top-off
__global__ void refine_kernel(const float* __restrict__ embv,
                              const float* __restrict__ embt,
                              const float* __restrict__ enc,
                              const float* __restrict__ invA,
                              const float* __restrict__ invB,
                              float* __restrict__ latent,
                              int* __restrict__ sel_cnt,
                              int* __restrict__ sel_idx,
                              float* __restrict__ sel_val,
                              const int* __restrict__ amb_cnt,
                              const int* __restrict__ amb_idx)
{
    int row = blockIdx.x;
    int s = amb_cnt[row];
    if (s == 0) return;
    int tid = threadIdx.x;
    int m = sel_cnt[row];
    int need = TOPK - m;
    float* v = latent + (size_t)row * H_DIM;
    if (need <= 0) return;                 // ambiguous slots already zero
    __shared__ float ex[AMB_CAP];
    __shared__ int evs, kc;
    const float* src = (row < N_ROWS) ? embv + (size_t)row * D_DIM
                                      : embt + (size_t)(row - N_ROWS) * D_DIM;
    float ia = invA[row];
    int wave = tid >> 6, lane = tid & 63;
    for (int a = wave; a < s; a += 4) {
        int h = amb_idx[(size_t)row * AMB_CAP + a];
        const float* w = enc + (size_t)h * D_DIM;
        float d = 0.f;
        for (int t = lane; t < D_DIM; t += 64) d += src[t] * w[t];
        #pragma unroll
        for (int o = 32; o > 0; o >>= 1) d += __shfl_down(d, o);
        if (lane == 0) {
            float cosv = d * ia * invB[h];
            ex[a] = 2.f - sqrtf(fmaxf(2.f - 2.f * cosv, 0.f));
        }
    }
    if (tid == 0) { evs = 0x7FFFFFFF; kc = 0; }
    __syncthreads();
    if (tid < s) {
        float mya = fabsf(ex[tid]);
        int g = 0;
        for (int j = 0; j < s; j++) {
            float aj = fabsf(ex[j]);
            g += (aj > mya || (aj == mya && j < tid)) ? 1 : 0;
        }
        if (g <= need) atomicMin(&evs, __float_as_int(mya));
    }
    __syncthreads();
    float ep = __int_as_float(evs);
    if (tid < s) {
        int idx = amb_idx[(size_t)row * AMB_CAP + tid];
        float e = ex[tid];
        if (fabsf(e) > ep) {
            int sl = atomicAdd(&kc, 1);
            v[idx] = e;
            sel_idx[(size_t)row * SEL_CAP + m + sl] = idx;
            sel_val[(size_t)row * SEL_CAP + m + sl] = e;
        }
    }
    __syncthreads();
    if (tid == 0) sel_cnt[row] = m + kc;
}

// ---------------------------------------------------------------------------
__global__ void transpose_kernel(const float* __restrict__ Wv,
                                 const float* __restrict__ Wt,
                                 float* __restrict__ WvT,
                                 float* __restrict__ WtT)
{
    int z = blockIdx.z;
    const float* W = z ? Wt : Wv;
    float* WT = z ? WtT : WvT;
    __shared__ float tile[32][33];
    int tx = threadIdx.x & 31;
    int ty = threadIdx.x >> 5;
    int h0 = blockIdx.x * 32;
    int d0 = blockIdx.y * 32;
    #pragma unroll
    for (int t = 0; t < 4; t++)
        tile[ty + t * 8][tx] = W[(size_t)(d0 + ty + t * 8) * H_DIM + h0 + tx];
    __syncthreads();
    #pragma unroll
    for (int t = 0; t < 4; t++)
        WT[(size_t)(h0 + ty + t * 8) * D_DIM + d0 + tx] = tile[tx][ty + t * 8];
}

// ---------------------------------------------------------------------------
__global__ void recon_kernel(const float* __restrict__ Wv_,
                             const float* __restrict__ Wt_,
                             const float* __restrict__ bv,
                             const float* __restrict__ bt,
                             const int* __restrict__ sel_cnt,
                             const int* __restrict__ sel_idx,
                             const float* __restrict__ sel_val,
                             long sh, long sd,
                             float* __restrict__ out)
{
    int n = blockIdx.x;
    int z = blockIdx.y;
    int row = z * N_ROWS + n;
    const float* W = z ? Wt_ : Wv_;
    const float* bias = z ? bt : bv;
    float* o = out + (size_t)z * N_ROWS * D_DIM + (size_t)n * D_DIM;

    __shared__ int s_idx[SEL_CAP];
    __shared__ float s_val[SEL_CAP];
    __shared__ int s_cnt;
    int tid = threadIdx.x;
    if (tid == 0) s_cnt = sel_cnt[row];
    __syncthreads();
    int cnt = s_cnt;
    if (tid < cnt) {
        s_idx[tid] = sel_idx[(size_t)row * SEL_CAP + tid];
        s_val[tid] = sel_val[(size_t)row * SEL_CAP + tid];
    }
    __syncthreads();

    for (int d = tid; d < D_DIM; d += 256) {
        float acc = bias[d];
        for (int j = 0; j < cnt; j++)
            acc += s_val[j] * W[(size_t)s_idx[j] * sh + (size_t)d * sd];
        o[d] = acc;
    }
}

// ============================ LEGACY FALLBACK ==============================
__global__ void row_invnorm_kernel(const float* __restrict__ x,
                                   float* __restrict__ inv, int rows) {
    int row = blockIdx.x * 4 + (threadIdx.x >> 6);
    int lane = threadIdx.x & 63;
    if (row >= rows) return;
    const float4* p = reinterpret_cast<const float4*>(x + (size_t)row * D_DIM);
    float ss = 0.f;
    #pragma unroll
    for (int i = 0; i < 3; i++) {
        float4 v = p[lane + i * 64];
        ss += v.x * v.x + v.y * v.y + v.z * v.z + v.w * v.w;
    }
    #pragma unroll
    for (int off = 32; off > 0; off >>= 1) ss += __shfl_down(ss, off);
    if (lane == 0) inv[row] = 1.f / fmaxf(sqrtf(ss), 1e-12f);
}

#define BM 128
#define BN 128
#define BK 16
__global__ __launch_bounds__(256)
void gemm_sim_kernel(const float* __restrict__ embv,
                     const float* __restrict__ embt,
                     const float* __restrict__ enc,
                     const float* __restrict__ inv_emb,
                     const float* __restrict__ inv_enc,
                     float* __restrict__ latent)
{
    int z = blockIdx.z;
    const float* A = z ? embt : embv;
    const float* invA = inv_emb + z * N_ROWS;
    float* C = latent + (size_t)z * N_ROWS * H_DIM;
    __shared__ float As[BK][BM + 4];
    __shared__ float Bs[BK][BN + 4];
    int tid = threadIdx.x;
    int tx = tid & 15, ty = tid >> 4;
    int row0 = blockIdx.y * BM, col0 = blockIdx.x * BN;
    float acc[8][8];
    #pragma unroll
    for (int i = 0; i < 8; i++)
        #pragma unroll
        for (int j = 0; j < 8; j++) acc[i][j] = 0.f;
    for (int k0 = 0; k0 < D_DIM; k0 += BK) {
        #pragma unroll
        for (int t = 0; t < 2; t++) {
            int idx = t * 256 + tid;
            int r = idx >> 2, c4 = idx & 3;
            float4 va = *reinterpret_cast<const float4*>(
                A + (size_t)(row0 + r) * D_DIM + k0 + c4 * 4);
            As[c4 * 4 + 0][r] = va.x; As[c4 * 4 + 1][r] = va.y;
            As[c4 * 4 + 2][r] = va.z; As[c4 * 4 + 3][r] = va.w;
            float4 vb = *reinterpret_cast<const float4*>(
                enc + (size_t)(col0 + r) * D_DIM + k0 + c4 * 4);
            Bs[c4 * 4 + 0][r] = vb.x; Bs[c4 * 4 + 1][r] = vb.y;
            Bs[c4 * 4 + 2][r] = vb.z; Bs[c4 * 4 + 3][r] = vb.w;
        }
        __syncthreads();
        #pragma unroll
        for (int kk = 0; kk < BK; kk++) {
            float a[8], b[8];
            *reinterpret_cast<float4*>(&a[0]) = *reinterpret_cast<const float4*>(&As[kk][ty * 8]);
            *reinterpret_cast<float4*>(&a[4]) = *reinterpret_cast<const float4*>(&As[kk][ty * 8 + 4]);
            *reinterpret_cast<float4*>(&b[0]) = *reinterpret_cast<const float4*>(&Bs[kk][tx * 8]);
            *reinterpret_cast<float4*>(&b[4]) = *reinterpret_cast<const float4*>(&Bs[kk][tx * 8 + 4]);
            #pragma unroll
            for (int i = 0; i < 8; i++)
                #pragma unroll
                for (int j = 0; j < 8; j++)
                    acc[i][j] = fmaf(a[i], b[j], acc[i][j]);
        }
        __syncthreads();
    }
    #pragma unroll
    for (int i = 0; i < 8; i++) {
        int n = row0 + ty * 8 + i;
        float sa = invA[n];
        float* Crow = C + (size_t)n * H_DIM + col0 + tx * 8;
        float tmp[8];
        #pragma unroll
        for (int j = 0; j < 8; j++) {
            float cosv = acc[i][j] * sa * inv_enc[col0 + tx * 8 + j];
            tmp[j] = 2.f - sqrtf(fmaxf(2.f - 2.f * cosv, 0.f));
        }
        float4 o0 = {tmp[0], tmp[1], tmp[2], tmp[3]};
        float4 o1 = {tmp[4], tmp[5], tmp[6], tmp[7]};
        *reinterpret_cast<float4*>(Crow) = o0;
        *reinterpret_cast<float4*>(Crow + 4) = o1;
    }
}

__global__ void legacy_select_kernel(float* __restrict__ latent,
                                     const int* __restrict__ topk_p,
                                     int* __restrict__ sel_cnt,
                                     int* __restrict__ sel_idx,
                                     float* __restrict__ sel_val)
{
    int row = blockIdx.x;
    float* v = latent + (size_t)row * H_DIM;
    int tid = threadIdx.x;
    __shared__ unsigned hist[256];
    __shared__ unsigned s_prefix;
    __shared__ int s_k;
    __shared__ int s_cnt;
    int k = topk_p[0] + 1;
    unsigned prefix = 0;
    for (int shift = 24; shift >= 0; shift -= 8) {
        hist[tid] = 0;
        __syncthreads();
        unsigned pmask = (shift == 24) ? 0u : (0xFFFFFFFFu << (shift + 8));
        for (int i = tid; i < H_DIM; i += 256) {
            unsigned u = __float_as_uint(v[i]) & 0x7FFFFFFFu;
            if ((u & pmask) == prefix)
                atomicAdd(&hist[(u >> shift) & 255u], 1u);
        }
        __syncthreads();
        if (tid == 0) {
            int c = 0, b = 255;
            for (; b >= 0; b--) {
                c += (int)hist[b];
                if (c >= k) break;
            }
            if (b < 0) b = 0;
            s_prefix = prefix | ((unsigned)b << shift);
            s_k = k - (c - (int)hist[b]);
        }
        __syncthreads();
        prefix = s_prefix;
        k = s_k;
        __syncthreads();
    }
    float thres = __uint_as_float(prefix);
    if (tid == 0) s_cnt = 0;
    __syncthreads();
    for (int i = tid; i < H_DIM; i += 256) {
        float x = v[i];
        bool keep = (fabsf(x) > thres);
        v[i] = keep ? x : 0.f;
        if (keep) {
            int slot = atomicAdd(&s_cnt, 1);
            if (slot < SEL_CAP) {
                sel_idx[(size_t)row * SEL_CAP + slot] = i;
                sel_val[(size_t)row * SEL_CAP + slot] = x;
            }
        }
    }
    __syncthreads();
    if (tid == 0) sel_cnt[row] = (s_cnt > SEL_CAP) ? SEL_CAP : s_cnt;
}

// ---------------------------------------------------------------------------
extern "C" void kernel_launch(void* const* d_in, const int* in_sizes, int n_in,
                              void* d_out, int out_size, void* d_ws, size_t ws_size,
                              hipStream_t stream) {
    const float* embv = (const float*)d_in[0];
    const float* embt = (const float*)d_in[1];
    const float* enc  = (const float*)d_in[2];
    const float* Wv   = (const float*)d_in[3];
    const float* bv   = (const float*)d_in[4];
    const float* Wt   = (const float*)d_in[5];
    const float* bt   = (const float*)d_in[6];
    const int* topk   = (const int*)d_in[7];
    float* out = (float*)d_out;

    float* recon_out = out;                              // [2][N][D]
    float* latent = out + (size_t)2 * N_ROWS * D_DIM;    // [2][N][H]

    char* ws = (char*)d_ws;
    size_t off = 0;
    float* invA = (float*)(ws + off);            off += (size_t)M_TOT * 4;
    float* invB = (float*)(ws + off);            off += (size_t)H_DIM * 4;
    int*   sel_cnt = (int*)(ws + off);           off += (size_t)M_TOT * 4;
    int*   amb_cnt = (int*)(ws + off);           off += (size_t)M_TOT * 4;
    int*   sel_idx = (int*)(ws + off);           off += (size_t)M_TOT * SEL_CAP * 4;
    float* sel_val = (float*)(ws + off);         off += (size_t)M_TOT * SEL_CAP * 4;
    int*   amb_idx = (int*)(ws + off);           off += (size_t)M_TOT * AMB_CAP * 4;
    unsigned short* Ahi = (unsigned short*)(ws + off); off += (size_t)M_TOT * D_DIM * 2;
    unsigned short* Alo = (unsigned short*)(ws + off); off += (size_t)M_TOT * D_DIM * 2;
    unsigned short* Bh  = (unsigned short*)(ws + off); off += (size_t)H_DIM * D_DIM * 2;
    size_t core_need = off;
    float* WvT = (float*)(ws + off);
    float* WtT = WvT + (size_t)D_DIM * H_DIM;
    size_t full_need = off + (size_t)2 * D_DIM * H_DIM * 4;

    if (ws_size >= core_need) {
        bool use_T = ws_size >= full_need;

        split_all_kernel<<<2 * N_ROWS + H_DIM, 256, 0, stream>>>(
            embv, embt, enc, Ahi, Alo, Bh, invA, invB);

        gemm_mfma_kernel<<<dim3(H_DIM / 128, M_TOT / 128), 256, 0, stream>>>(
            Ahi, Alo, Bh, latent);

        select_kernel<<<M_TOT, 256, 0, stream>>>(latent,
            sel_cnt, sel_idx, sel_val, amb_cnt, amb_idx);

        refine_kernel<<<M_TOT, 256, 0, stream>>>(embv, embt, enc, invA, invB,
            latent, sel_cnt, sel_idx, sel_val, amb_cnt, amb_idx);

        if (use_T) {
            transpose_kernel<<<dim3(H_DIM / 32, D_DIM / 32, 2), 256, 0, stream>>>(
                Wv, Wt, WvT, WtT);
            recon_kernel<<<dim3(N_ROWS, 2), 256, 0, stream>>>(
                WvT, WtT, bv, bt, sel_cnt, sel_idx, sel_val, (long)D_DIM, 1L, recon_out);
        } else {
            recon_kernel<<<dim3(N_ROWS, 2), 256, 0, stream>>>(
                Wv, Wt, bv, bt, sel_cnt, sel_idx, sel_val, 1L, (long)H_DIM, recon_out);
        }
    } else {
        // legacy all-fp32 path (small workspace)
        size_t o2 = 0;
        float* inv_enc = (float*)(ws + o2); o2 += (size_t)H_DIM * 4;
        float* inv_emb = (float*)(ws + o2); o2 += (size_t)2 * N_ROWS * 4;
        int*   l_cnt = (int*)(ws + o2);     o2 += (size_t)2 * N_ROWS * 4;
        int*   l_idx = (int*)(ws + o2);     o2 += (size_t)2 * N_ROWS * SEL_CAP * 4;
        float* l_val = (float*)(ws + o2);   o2 += (size_t)2 * N_ROWS * SEL_CAP * 4;
        row_invnorm_kernel<<<H_DIM / 4, 256, 0, stream>>>(enc, inv_enc, H_DIM);
        row_invnorm_kernel<<<N_ROWS / 4, 256, 0, stream>>>(embv, inv_emb, N_ROWS);
        row_invnorm_kernel<<<N_ROWS / 4, 256, 0, stream>>>(embt, inv_emb + N_ROWS, N_ROWS);
        dim3 g(H_DIM / BN, N_ROWS / BM, 2);
        gemm_sim_kernel<<<g, 256, 0, stream>>>(embv, embt, enc, inv_emb, inv_enc, latent);
        legacy_select_kernel<<<2 * N_ROWS, 256, 0, stream>>>(latent, topk, l_cnt, l_idx, l_val);
        recon_kernel<<<dim3(N_ROWS, 2), 256, 0, stream>>>(
            Wv, Wt, bv, bt, l_cnt, l_idx, l_val, 1L, (long)H_DIM, recon_out);
    }
}